// Round 11
// baseline (174.870 us; speedup 1.0000x reference)
//
#include <hip/hip_runtime.h>
#include <hip/hip_bf16.h>

typedef __attribute__((ext_vector_type(8))) short short8;
typedef __attribute__((ext_vector_type(4))) float f32x4;

#define S_LEN 2048
#define NH 16
#define NKV 8
#define HD 64
#define WIN 512
#define DMODEL 1024
#define LOG2_10000 13.287712379549449f

// async 16B global -> LDS (wave-uniform LDS base + lane*16 semantics)
#define GLOAD16(g, l)                                                        \
    __builtin_amdgcn_global_load_lds(                                        \
        (const __attribute__((address_space(1))) unsigned int*)(g),          \
        (__attribute__((address_space(3))) unsigned int*)(l), 16, 0, 0)

// ---------------- cast X (fp32 -> bf16), vectorized ----------------
__global__ void cast_bf16_kernel(const float* __restrict__ X,
                                 __hip_bfloat16* __restrict__ Y, int n) {
    int i = (blockIdx.x * 256 + threadIdx.x) * 4;
    if (i + 3 < n) {
        float4 v = *reinterpret_cast<const float4*>(X + i);
        Y[i + 0] = __float2bfloat16(v.x);
        Y[i + 1] = __float2bfloat16(v.y);
        Y[i + 2] = __float2bfloat16(v.z);
        Y[i + 3] = __float2bfloat16(v.w);
    }
}

// ------- fused transpose+cast of all 4 weights (z selects matrix) -------
__global__ void transpose_cast4_kernel(const float* __restrict__ W0,
                                       const float* __restrict__ W1,
                                       const float* __restrict__ W2,
                                       const float* __restrict__ W3,
                                       __hip_bfloat16* __restrict__ WqkvT,
                                       __hip_bfloat16* __restrict__ WoT) {
    __shared__ float tile[32][33];
    const int K = DMODEL;
    const float* W;
    __hip_bfloat16* WT;
    int N;
    switch (blockIdx.z) {
        case 0: W = W0; WT = WqkvT;                          N = 1024; break;
        case 1: W = W1; WT = WqkvT + (size_t)1024 * K;       N = 512;  break;
        case 2: W = W2; WT = WqkvT + (size_t)1536 * K;       N = 512;  break;
        default: W = W3; WT = WoT;                           N = 1024; break;
    }
    if ((int)blockIdx.x * 32 >= N) return;
    int nx = blockIdx.x * 32 + threadIdx.x;
    int k0 = blockIdx.y * 32;
#pragma unroll
    for (int r = 0; r < 4; ++r) {
        int k = k0 + threadIdx.y + r * 8;
        tile[threadIdx.y + r * 8][threadIdx.x] = W[(size_t)k * N + nx];
    }
    __syncthreads();
#pragma unroll
    for (int r = 0; r < 4; ++r) {
        int nn = blockIdx.x * 32 + threadIdx.y + r * 8;
        int kk = k0 + threadIdx.x;
        WT[(size_t)nn * K + kk] = __float2bfloat16(tile[threadIdx.x][threadIdx.y + r * 8]);
    }
}

// ---------------- m97-geometry GEMM: 128x128 tile, 256 thr = 4 waves ----------
// Wave tile 64x64 (4x4 MFMA 16x16x32) -> 16 MFMA : 8 ds_read_b128 per iter.
// MODE 0: fused QKV epilogue, in-register RoPE on Q/K (__cosf/__sinf ONLY —
//         libm calls spill the acc array). MODE 1: fp32 C.
template <int MODE>
__global__ __launch_bounds__(256) void gemm256_kernel(
    const __hip_bfloat16* __restrict__ A,
    const __hip_bfloat16* __restrict__ BT,
    void* __restrict__ o0, void* __restrict__ o1, void* __restrict__ o2,
    int N, int K) {
    __shared__ __hip_bfloat16 ldsA[128 * 32];   // 8 KB
    __shared__ __hip_bfloat16 ldsB[128 * 32];   // 8 KB
    const int tx = threadIdx.x;
    const int wave = tx >> 6;
    const int lane = tx & 63;
    const int l16 = lane & 15;
    const int quad = lane >> 4;
    const int col0 = blockIdx.x * 128;
    const int row0 = blockIdx.y * 128;
    const int wrow = (wave >> 1) * 64;
    const int wcol = (wave & 1) * 64;

    f32x4 acc[4][4] = {};

    const int arow = tx >> 2;            // 0..63
    const int kc8 = (tx & 3) * 8;
    const __hip_bfloat16* gA = A + (size_t)(row0 + arow) * K + kc8;
    const __hip_bfloat16* gB = BT + (size_t)(col0 + arow) * K + kc8;
    char* lA = (char*)ldsA + tx * 16;
    char* lB = (char*)ldsB + tx * 16;

    for (int k0 = 0; k0 < K; k0 += 32) {
        GLOAD16(gA + k0, lA);
        GLOAD16(gA + (size_t)64 * K + k0, lA + 4096);
        GLOAD16(gB + k0, lB);
        GLOAD16(gB + (size_t)64 * K + k0, lB + 4096);
        __syncthreads();
        short8 af[4], bf[4];
#pragma unroll
        for (int i = 0; i < 4; ++i) {
            af[i] = *reinterpret_cast<const short8*>(
                ldsA + (wrow + i * 16 + l16) * 32 + quad * 8);
            bf[i] = *reinterpret_cast<const short8*>(
                ldsB + (wcol + i * 16 + l16) * 32 + quad * 8);
        }
#pragma unroll
        for (int mi = 0; mi < 4; ++mi)
#pragma unroll
            for (int ni = 0; ni < 4; ++ni)
                acc[mi][ni] = __builtin_amdgcn_mfma_f32_16x16x32_bf16(
                    af[mi], bf[ni], acc[mi][ni], 0, 0, 0);
        __syncthreads();
    }

    const int rbase = row0 + wrow;
    if (MODE == 0) {
        const int cbaseg = col0 + wcol;             // 64-aligned global col
        const bool isQ = (cbaseg < DMODEL);
        const bool isK = (cbaseg >= DMODEL) && (cbaseg < DMODEL + 512);
        if (isQ || isK) {
            float invf[2];
            invf[0] = exp2f(-(float)(l16)      * (LOG2_10000 / 32.0f));
            invf[1] = exp2f(-(float)(16 + l16) * (LOG2_10000 / 32.0f));
#pragma unroll
            for (int mi = 0; mi < 4; ++mi)
#pragma unroll
                for (int r = 0; r < 4; ++r) {
                    int srow = (rbase + mi * 16 + quad * 4 + r) & (S_LEN - 1);
#pragma unroll
                    for (int ni = 0; ni < 2; ++ni) {
                        float ang = (float)srow * invf[ni];
                        float c = __cosf(ang), s = __sinf(ang);
                        float x1 = acc[mi][ni][r], x2 = acc[mi][ni + 2][r];
                        acc[mi][ni][r]     = x1 * c - x2 * s;
                        acc[mi][ni + 2][r] = x2 * c + x1 * s;
                    }
                }
            __hip_bfloat16* Co = (__hip_bfloat16*)(isQ ? o0 : o1);
            int cbase = isQ ? cbaseg : cbaseg - DMODEL;
            int rowstride = isQ ? (NH * HD) : (NKV * HD);
#pragma unroll
            for (int mi = 0; mi < 4; ++mi)
#pragma unroll
                for (int ni = 0; ni < 4; ++ni) {
                    size_t col = cbase + ni * 16 + l16;
#pragma unroll
                    for (int r = 0; r < 4; ++r)
                        Co[(size_t)(rbase + mi * 16 + quad * 4 + r) * rowstride + col] =
                            __float2bfloat16(acc[mi][ni][r]);
                }
        } else {                                   // V region -> transposed VT
            __hip_bfloat16* VTo = (__hip_bfloat16*)o2;
            int bb = row0 >> 11;
#pragma unroll
            for (int mi = 0; mi < 4; ++mi) {
                int s = ((rbase + mi * 16 + quad * 4) & (S_LEN - 1));
#pragma unroll
                for (int ni = 0; ni < 4; ++ni) {
                    int colv = cbaseg - 1536 + ni * 16 + l16;   // 0..511
                    int vh = colv >> 6, d = colv & 63;
                    alignas(8) __hip_bfloat16 hv[4];
#pragma unroll
                    for (int r = 0; r < 4; ++r) hv[r] = __float2bfloat16(acc[mi][ni][r]);
                    *reinterpret_cast<ushort4*>(
                        VTo + ((size_t)(bb * NKV + vh) * HD + d) * S_LEN + s) =
                        *reinterpret_cast<ushort4*>(hv);
                }
            }
        }
    } else {                                       // fp32 C
        float* Co = (float*)o0;
#pragma unroll
        for (int mi = 0; mi < 4; ++mi)
#pragma unroll
            for (int ni = 0; ni < 4; ++ni) {
                size_t col = col0 + wcol + ni * 16 + l16;
#pragma unroll
                for (int r = 0; r < 4; ++r)
                    Co[(size_t)(rbase + mi * 16 + quad * 4 + r) * N + col] = acc[mi][ni][r];
            }
    }
}

// ---------------- MFMA flash attention: GQA head-shared, DMA dbuf, swizzled ----
// ROUND 11: attn is latency-bound (throughput floor ~5us, measured ~38us;
// 9 serial chunk chains x ~500cy, only 3 blocks/CU to interleave). GQA fix:
// one block per KV head (grid 32 x NKV x B) computes BOTH Q-heads sharing
// that K/V — staging + K-fragment ds_reads shared across heads (8 reads feed
// 16 MFMAs), two independent softmax chains per wave (2x ILP on the critical
// path), half the blocks, half the KV fetch. P gets a per-head slot.
__global__ __launch_bounds__(256, 3) void attn_mfma_kernel(
    const __hip_bfloat16* __restrict__ Q,
    const __hip_bfloat16* __restrict__ K,
    const __hip_bfloat16* __restrict__ VT,
    __hip_bfloat16* __restrict__ O) {
    __shared__ __hip_bfloat16 ldsK[2][64][64];       // 16 KB
    __shared__ __hip_bfloat16 ldsVT[2][64][64];      // 16 KB
    __shared__ __hip_bfloat16 ldsP[4][2][16][80];    // 20.5 KB
    const int tx = threadIdx.x;
    const int wave = tx >> 6;
    const int lane = tx & 63;
    const int l16 = lane & 15;
    const int quad = lane >> 4;
    const int q0 = blockIdx.x * 64;
    const int kvh = blockIdx.y;
    const int b = blockIdx.z;
    const int qi = q0 + wave * 16 + l16;

    short8 aq[2][2];
#pragma unroll
    for (int hh = 0; hh < 2; ++hh) {
        const __hip_bfloat16* qp =
            Q + (size_t)(b * S_LEN + qi) * (NH * HD) + (2 * kvh + hh) * HD + quad * 8;
        aq[hh][0] = *reinterpret_cast<const short8*>(qp);
        aq[hh][1] = *reinterpret_cast<const short8*>(qp + 32);
    }
    f32x4 acc_o[2][4] = {};
    float m[2] = {-1e30f, -1e30f}, l[2] = {0.f, 0.f};
    const float SL2 = 0.125f * 1.4426950408889634f;   // scale * log2(e)

    // staging: row = tx>>3 (+32), chunk-in-row = tx&7, XOR source swizzle
    const int s_row = tx >> 3;
    const int s_c8 = (((tx & 7) ^ (s_row & 7))) * 8;
    const int sw = (l16 & 7);                          // reader swizzle key
    auto stage = [&](int j0, int bf) {
        char* lk = (char*)(&ldsK[bf][0][0]) + tx * 16;
        char* lv = (char*)(&ldsVT[bf][0][0]) + tx * 16;
#pragma unroll
        for (int r = 0; r < 2; ++r) {
            int row = s_row + r * 32;
            GLOAD16(K + (size_t)(b * S_LEN + j0 + row) * (NKV * HD) + kvh * HD + s_c8,
                    lk + r * 4096);
            GLOAD16(VT + ((size_t)(b * NKV + kvh) * HD + row) * S_LEN + j0 + s_c8,
                    lv + r * 4096);
        }
    };

    const int kstart = (q0 >= WIN) ? (q0 - WIN) : 0;
    stage(kstart, 0);
    int buf = 0;

    for (int j0 = kstart; j0 <= q0; j0 += 64) {
        __syncthreads();                              // drains DMA into [buf]
        if (j0 + 64 <= q0) stage(j0 + 64, buf ^ 1);   // async, lands by next barrier

        // S^T = K @ Q^T for BOTH heads; K fragments read once
        f32x4 sacc[2][4] = {};
#pragma unroll
        for (int t = 0; t < 4; ++t) {
            const __hip_bfloat16* krow = &ldsK[buf][t * 16 + l16][0];
            short8 bk0 = *reinterpret_cast<const short8*>(krow + ((quad ^ sw) * 8));
            short8 bk1 = *reinterpret_cast<const short8*>(krow + (((4 + quad) ^ sw) * 8));
            sacc[0][t] = __builtin_amdgcn_mfma_f32_16x16x32_bf16(bk0, aq[0][0], sacc[0][t], 0, 0, 0);
            sacc[0][t] = __builtin_amdgcn_mfma_f32_16x16x32_bf16(bk1, aq[0][1], sacc[0][t], 0, 0, 0);
            sacc[1][t] = __builtin_amdgcn_mfma_f32_16x16x32_bf16(bk0, aq[1][0], sacc[1][t], 0, 0, 0);
            sacc[1][t] = __builtin_amdgcn_mfma_f32_16x16x32_bf16(bk1, aq[1][1], sacc[1][t], 0, 0, 0);
        }

        const bool need_mask = (j0 == q0) || (q0 >= WIN && j0 == kstart);
#pragma unroll
        for (int hh = 0; hh < 2; ++hh) {
            float sv[4][4];
            if (need_mask) {
#pragma unroll
                for (int t = 0; t < 4; ++t)
#pragma unroll
                    for (int r = 0; r < 4; ++r) {
                        int j = j0 + t * 16 + quad * 4 + r;
                        bool ok = (j <= qi) && (j + WIN >= qi);
                        sv[t][r] = ok ? sacc[hh][t][r] * SL2 : -1e30f;
                    }
            } else {
#pragma unroll
                for (int t = 0; t < 4; ++t)
#pragma unroll
                    for (int r = 0; r < 4; ++r) sv[t][r] = sacc[hh][t][r] * SL2;
            }
            // online softmax (exp2 domain): in-lane reduce + 2 shuffles
            float cm = -1e30f;
#pragma unroll
            for (int t = 0; t < 4; ++t)
#pragma unroll
                for (int r = 0; r < 4; ++r) cm = fmaxf(cm, sv[t][r]);
            cm = fmaxf(cm, __shfl_xor(cm, 16));
            cm = fmaxf(cm, __shfl_xor(cm, 32));
            float mn = fmaxf(m[hh], cm);
            float alpha = exp2f(m[hh] - mn);
            m[hh] = mn;
            float sp = 0.f;
#pragma unroll
            for (int t = 0; t < 4; ++t)
#pragma unroll
                for (int r = 0; r < 4; ++r) { sv[t][r] = exp2f(sv[t][r] - mn); sp += sv[t][r]; }
            sp += __shfl_xor(sp, 16);
            sp += __shfl_xor(sp, 32);
            l[hh] = l[hh] * alpha + sp;
#pragma unroll
            for (int t = 0; t < 4; ++t)
#pragma unroll
                for (int r = 0; r < 4; ++r) acc_o[hh][t][r] *= alpha;
            // P^T -> per-head LDS slot (packed b64; wave-private, in-order)
#pragma unroll
            for (int t = 0; t < 4; ++t) {
                alignas(8) __hip_bfloat16 hp[4];
#pragma unroll
                for (int r = 0; r < 4; ++r) hp[r] = __float2bfloat16(sv[t][r]);
                *reinterpret_cast<ushort4*>(&ldsP[wave][hh][l16][t * 16 + quad * 4]) =
                    *reinterpret_cast<ushort4*>(hp);
            }
        }

        // O^T += VT @ P^T — VT fragments read once, feed both heads
#pragma unroll
        for (int ks = 0; ks < 2; ++ks) {
            short8 pf0 = *reinterpret_cast<const short8*>(
                &ldsP[wave][0][l16][ks * 32 + quad * 8]);
            short8 pf1 = *reinterpret_cast<const short8*>(
                &ldsP[wave][1][l16][ks * 32 + quad * 8]);
#pragma unroll
            for (int t = 0; t < 4; ++t) {
                const __hip_bfloat16* vrow = &ldsVT[buf][t * 16 + l16][0];
                short8 vf = *reinterpret_cast<const short8*>(
                    vrow + (((ks * 4 + quad) ^ sw) * 8));
                acc_o[0][t] = __builtin_amdgcn_mfma_f32_16x16x32_bf16(vf, pf0, acc_o[0][t], 0, 0, 0);
                acc_o[1][t] = __builtin_amdgcn_mfma_f32_16x16x32_bf16(vf, pf1, acc_o[1][t], 0, 0, 0);
            }
        }
        buf ^= 1;
    }

#pragma unroll
    for (int hh = 0; hh < 2; ++hh) {
        float inv = 1.f / l[hh];
        __hip_bfloat16* op =
            O + (size_t)(b * S_LEN + qi) * (NH * HD) + (2 * kvh + hh) * HD;
#pragma unroll
        for (int t = 0; t < 4; ++t) {
            alignas(8) __hip_bfloat16 ho[4];
#pragma unroll
            for (int r = 0; r < 4; ++r) ho[r] = __float2bfloat16(acc_o[hh][t][r] * inv);
            *reinterpret_cast<ushort4*>(op + t * 16 + quad * 4) =
                *reinterpret_cast<ushort4*>(ho);
        }
    }
}

// ---------------- launch ----------------
extern "C" void kernel_launch(void* const* d_in, const int* in_sizes, int n_in,
                              void* d_out, int out_size, void* d_ws, size_t ws_size,
                              hipStream_t stream) {
    const float* X  = (const float*)d_in[0];
    const float* Wq = (const float*)d_in[1];
    const float* Wk = (const float*)d_in[2];
    const float* Wv = (const float*)d_in[3];
    const float* Wo = (const float*)d_in[4];
    float* out = (float*)d_out;

    const int ROWS = 2 * S_LEN;               // 4096
    char* ws = (char*)d_ws;
    size_t off = 0;
    __hip_bfloat16* Xb     = (__hip_bfloat16*)(ws + off); off += (size_t)ROWS * DMODEL * 2;
    __hip_bfloat16* WqkvT  = (__hip_bfloat16*)(ws + off); off += (size_t)2048 * DMODEL * 2;
    __hip_bfloat16* WoT    = (__hip_bfloat16*)(ws + off); off += (size_t)DMODEL * DMODEL * 2;
    __hip_bfloat16* Qb     = (__hip_bfloat16*)(ws + off); off += (size_t)ROWS * (NH * HD) * 2;
    __hip_bfloat16* Kb     = (__hip_bfloat16*)(ws + off); off += (size_t)ROWS * (NKV * HD) * 2;
    __hip_bfloat16* VTg    = (__hip_bfloat16*)(ws + off); off += (size_t)ROWS * (NKV * HD) * 2;
    __hip_bfloat16* Ob     = (__hip_bfloat16*)(ws + off); off += (size_t)ROWS * (NH * HD) * 2;

    // 1. cast X; fused transpose of all weights
    cast_bf16_kernel<<<(ROWS * DMODEL) / (256 * 4), 256, 0, stream>>>(X, Xb, ROWS * DMODEL);
    transpose_cast4_kernel<<<dim3(32, 32, 4), dim3(32, 8), 0, stream>>>(
        Wq, Wk, Wv, Wo, WqkvT, WoT);

    // 2. fused QKV projection + in-register RoPE (Q,K) + V transpose
    gemm256_kernel<0><<<dim3(2048 / 128, ROWS / 128), 256, 0, stream>>>(
        Xb, WqkvT, Qb, Kb, VTg, 2048, DMODEL);

    // 3. MFMA flash attention (GQA head-shared, DMA dbuf, swizzled)
    attn_mfma_kernel<<<dim3(S_LEN / 64, NKV, 2), 256, 0, stream>>>(Qb, Kb, VTg, Ob);

    // 4. output projection -> fp32
    gemm256_kernel<1><<<dim3(DMODEL / 128, ROWS / 128), 256, 0, stream>>>(
        Ob, WoT, out, nullptr, nullptr, DMODEL, DMODEL);
}

// Round 12
// 167.754 us; speedup vs baseline: 1.0424x; 1.0424x over previous
//
#include <hip/hip_runtime.h>
#include <hip/hip_bf16.h>

typedef __attribute__((ext_vector_type(8))) short short8;
typedef __attribute__((ext_vector_type(4))) float f32x4;

#define S_LEN 2048
#define NH 16
#define NKV 8
#define HD 64
#define WIN 512
#define DMODEL 1024
#define LOG2_10000 13.287712379549449f

// async 16B global -> LDS (wave-uniform LDS base + lane*16 semantics)
#define GLOAD16(g, l)                                                        \
    __builtin_amdgcn_global_load_lds(                                        \
        (const __attribute__((address_space(1))) unsigned int*)(g),          \
        (__attribute__((address_space(3))) unsigned int*)(l), 16, 0, 0)

// ---------------- cast X (fp32 -> bf16), vectorized ----------------
__global__ void cast_bf16_kernel(const float* __restrict__ X,
                                 __hip_bfloat16* __restrict__ Y, int n) {
    int i = (blockIdx.x * 256 + threadIdx.x) * 4;
    if (i + 3 < n) {
        float4 v = *reinterpret_cast<const float4*>(X + i);
        Y[i + 0] = __float2bfloat16(v.x);
        Y[i + 1] = __float2bfloat16(v.y);
        Y[i + 2] = __float2bfloat16(v.z);
        Y[i + 3] = __float2bfloat16(v.w);
    }
}

// ------- fused transpose+cast of all 4 weights (z selects matrix) -------
__global__ void transpose_cast4_kernel(const float* __restrict__ W0,
                                       const float* __restrict__ W1,
                                       const float* __restrict__ W2,
                                       const float* __restrict__ W3,
                                       __hip_bfloat16* __restrict__ WqkvT,
                                       __hip_bfloat16* __restrict__ WoT) {
    __shared__ float tile[32][33];
    const int K = DMODEL;
    const float* W;
    __hip_bfloat16* WT;
    int N;
    switch (blockIdx.z) {
        case 0: W = W0; WT = WqkvT;                          N = 1024; break;
        case 1: W = W1; WT = WqkvT + (size_t)1024 * K;       N = 512;  break;
        case 2: W = W2; WT = WqkvT + (size_t)1536 * K;       N = 512;  break;
        default: W = W3; WT = WoT;                           N = 1024; break;
    }
    if ((int)blockIdx.x * 32 >= N) return;
    int nx = blockIdx.x * 32 + threadIdx.x;
    int k0 = blockIdx.y * 32;
#pragma unroll
    for (int r = 0; r < 4; ++r) {
        int k = k0 + threadIdx.y + r * 8;
        tile[threadIdx.y + r * 8][threadIdx.x] = W[(size_t)k * N + nx];
    }
    __syncthreads();
#pragma unroll
    for (int r = 0; r < 4; ++r) {
        int nn = blockIdx.x * 32 + threadIdx.y + r * 8;
        int kk = k0 + threadIdx.x;
        WT[(size_t)nn * K + kk] = __float2bfloat16(tile[threadIdx.x][threadIdx.y + r * 8]);
    }
}

// ---------------- m97-geometry GEMM + DMA double-buffer ----------------
// 128x128 tile, 256 thr = 4 waves, wave tile 64x64, BK=32.
// ROUND 12: the old loop issued GLOAD16 right before __syncthreads — the
// compiler's vmcnt(0) drain before s_barrier exposed full global latency
// every K-iter (same bug as r7 attention). Now double-buffered: stage k+1
// right AFTER the barrier; its drain lands at the NEXT barrier, one full
// compute section later. One barrier/iter, zero staging VGPRs.
// MODE 0: fused QKV epilogue, in-register RoPE on Q/K (__cosf/__sinf ONLY —
//         libm calls spill the acc array). MODE 1: fp32 C.
template <int MODE>
__global__ __launch_bounds__(256) void gemm256_kernel(
    const __hip_bfloat16* __restrict__ A,
    const __hip_bfloat16* __restrict__ BT,
    void* __restrict__ o0, void* __restrict__ o1, void* __restrict__ o2,
    int N, int K) {
    __shared__ __hip_bfloat16 ldsA[2][128 * 32];   // 16 KB
    __shared__ __hip_bfloat16 ldsB[2][128 * 32];   // 16 KB
    const int tx = threadIdx.x;
    const int wave = tx >> 6;
    const int lane = tx & 63;
    const int l16 = lane & 15;
    const int quad = lane >> 4;
    const int col0 = blockIdx.x * 128;
    const int row0 = blockIdx.y * 128;
    const int wrow = (wave >> 1) * 64;
    const int wcol = (wave & 1) * 64;

    f32x4 acc[4][4] = {};

    const int arow = tx >> 2;            // 0..63
    const int kc8 = (tx & 3) * 8;
    const __hip_bfloat16* gA = A + (size_t)(row0 + arow) * K + kc8;
    const __hip_bfloat16* gB = BT + (size_t)(col0 + arow) * K + kc8;

    auto stage = [&](int k0, int bf) {
        char* lA = (char*)(&ldsA[bf][0]) + tx * 16;
        char* lB = (char*)(&ldsB[bf][0]) + tx * 16;
        GLOAD16(gA + k0, lA);
        GLOAD16(gA + (size_t)64 * K + k0, lA + 4096);
        GLOAD16(gB + k0, lB);
        GLOAD16(gB + (size_t)64 * K + k0, lB + 4096);
    };

    stage(0, 0);
    int buf = 0;
    for (int k0 = 0; k0 < K; k0 += 32) {
        __syncthreads();                            // drains DMA into [buf]
        if (k0 + 32 < K) stage(k0 + 32, buf ^ 1);   // lands by next barrier
        short8 af[4], bf4[4];
#pragma unroll
        for (int i = 0; i < 4; ++i) {
            af[i] = *reinterpret_cast<const short8*>(
                &ldsA[buf][0] + (wrow + i * 16 + l16) * 32 + quad * 8);
            bf4[i] = *reinterpret_cast<const short8*>(
                &ldsB[buf][0] + (wcol + i * 16 + l16) * 32 + quad * 8);
        }
#pragma unroll
        for (int mi = 0; mi < 4; ++mi)
#pragma unroll
            for (int ni = 0; ni < 4; ++ni)
                acc[mi][ni] = __builtin_amdgcn_mfma_f32_16x16x32_bf16(
                    af[mi], bf4[ni], acc[mi][ni], 0, 0, 0);
        buf ^= 1;
    }

    const int rbase = row0 + wrow;
    if (MODE == 0) {
        const int cbaseg = col0 + wcol;             // 64-aligned global col
        const bool isQ = (cbaseg < DMODEL);
        const bool isK = (cbaseg >= DMODEL) && (cbaseg < DMODEL + 512);
        if (isQ || isK) {
            float invf[2];
            invf[0] = exp2f(-(float)(l16)      * (LOG2_10000 / 32.0f));
            invf[1] = exp2f(-(float)(16 + l16) * (LOG2_10000 / 32.0f));
#pragma unroll
            for (int mi = 0; mi < 4; ++mi)
#pragma unroll
                for (int r = 0; r < 4; ++r) {
                    int srow = (rbase + mi * 16 + quad * 4 + r) & (S_LEN - 1);
#pragma unroll
                    for (int ni = 0; ni < 2; ++ni) {
                        float ang = (float)srow * invf[ni];
                        float c = __cosf(ang), s = __sinf(ang);
                        float x1 = acc[mi][ni][r], x2 = acc[mi][ni + 2][r];
                        acc[mi][ni][r]     = x1 * c - x2 * s;
                        acc[mi][ni + 2][r] = x2 * c + x1 * s;
                    }
                }
            __hip_bfloat16* Co = (__hip_bfloat16*)(isQ ? o0 : o1);
            int cbase = isQ ? cbaseg : cbaseg - DMODEL;
            int rowstride = isQ ? (NH * HD) : (NKV * HD);
#pragma unroll
            for (int mi = 0; mi < 4; ++mi)
#pragma unroll
                for (int ni = 0; ni < 4; ++ni) {
                    size_t col = cbase + ni * 16 + l16;
#pragma unroll
                    for (int r = 0; r < 4; ++r)
                        Co[(size_t)(rbase + mi * 16 + quad * 4 + r) * rowstride + col] =
                            __float2bfloat16(acc[mi][ni][r]);
                }
        } else {                                   // V region -> transposed VT
            __hip_bfloat16* VTo = (__hip_bfloat16*)o2;
            int bb = row0 >> 11;
#pragma unroll
            for (int mi = 0; mi < 4; ++mi) {
                int s = ((rbase + mi * 16 + quad * 4) & (S_LEN - 1));
#pragma unroll
                for (int ni = 0; ni < 4; ++ni) {
                    int colv = cbaseg - 1536 + ni * 16 + l16;   // 0..511
                    int vh = colv >> 6, d = colv & 63;
                    alignas(8) __hip_bfloat16 hv[4];
#pragma unroll
                    for (int r = 0; r < 4; ++r) hv[r] = __float2bfloat16(acc[mi][ni][r]);
                    *reinterpret_cast<ushort4*>(
                        VTo + ((size_t)(bb * NKV + vh) * HD + d) * S_LEN + s) =
                        *reinterpret_cast<ushort4*>(hv);
                }
            }
        }
    } else {                                       // fp32 C
        float* Co = (float*)o0;
#pragma unroll
        for (int mi = 0; mi < 4; ++mi)
#pragma unroll
            for (int ni = 0; ni < 4; ++ni) {
                size_t col = col0 + wcol + ni * 16 + l16;
#pragma unroll
                for (int r = 0; r < 4; ++r)
                    Co[(size_t)(rbase + mi * 16 + quad * 4 + r) * N + col] = acc[mi][ni][r];
            }
    }
}

// ---------------- MFMA flash attention: GQA head-shared, DMA dbuf, swizzled ----
__global__ __launch_bounds__(256, 3) void attn_mfma_kernel(
    const __hip_bfloat16* __restrict__ Q,
    const __hip_bfloat16* __restrict__ K,
    const __hip_bfloat16* __restrict__ VT,
    __hip_bfloat16* __restrict__ O) {
    __shared__ __hip_bfloat16 ldsK[2][64][64];       // 16 KB
    __shared__ __hip_bfloat16 ldsVT[2][64][64];      // 16 KB
    __shared__ __hip_bfloat16 ldsP[4][2][16][80];    // 20.5 KB
    const int tx = threadIdx.x;
    const int wave = tx >> 6;
    const int lane = tx & 63;
    const int l16 = lane & 15;
    const int quad = lane >> 4;
    const int q0 = blockIdx.x * 64;
    const int kvh = blockIdx.y;
    const int b = blockIdx.z;
    const int qi = q0 + wave * 16 + l16;

    short8 aq[2][2];
#pragma unroll
    for (int hh = 0; hh < 2; ++hh) {
        const __hip_bfloat16* qp =
            Q + (size_t)(b * S_LEN + qi) * (NH * HD) + (2 * kvh + hh) * HD + quad * 8;
        aq[hh][0] = *reinterpret_cast<const short8*>(qp);
        aq[hh][1] = *reinterpret_cast<const short8*>(qp + 32);
    }
    f32x4 acc_o[2][4] = {};
    float m[2] = {-1e30f, -1e30f}, l[2] = {0.f, 0.f};
    const float SL2 = 0.125f * 1.4426950408889634f;   // scale * log2(e)

    // staging: row = tx>>3 (+32), chunk-in-row = tx&7, XOR source swizzle
    const int s_row = tx >> 3;
    const int s_c8 = (((tx & 7) ^ (s_row & 7))) * 8;
    const int sw = (l16 & 7);                          // reader swizzle key
    auto stage = [&](int j0, int bf) {
        char* lk = (char*)(&ldsK[bf][0][0]) + tx * 16;
        char* lv = (char*)(&ldsVT[bf][0][0]) + tx * 16;
#pragma unroll
        for (int r = 0; r < 2; ++r) {
            int row = s_row + r * 32;
            GLOAD16(K + (size_t)(b * S_LEN + j0 + row) * (NKV * HD) + kvh * HD + s_c8,
                    lk + r * 4096);
            GLOAD16(VT + ((size_t)(b * NKV + kvh) * HD + row) * S_LEN + j0 + s_c8,
                    lv + r * 4096);
        }
    };

    const int kstart = (q0 >= WIN) ? (q0 - WIN) : 0;
    stage(kstart, 0);
    int buf = 0;

    for (int j0 = kstart; j0 <= q0; j0 += 64) {
        __syncthreads();                              // drains DMA into [buf]
        if (j0 + 64 <= q0) stage(j0 + 64, buf ^ 1);   // async, lands by next barrier

        // S^T = K @ Q^T for BOTH heads; K fragments read once
        f32x4 sacc[2][4] = {};
#pragma unroll
        for (int t = 0; t < 4; ++t) {
            const __hip_bfloat16* krow = &ldsK[buf][t * 16 + l16][0];
            short8 bk0 = *reinterpret_cast<const short8*>(krow + ((quad ^ sw) * 8));
            short8 bk1 = *reinterpret_cast<const short8*>(krow + (((4 + quad) ^ sw) * 8));
            sacc[0][t] = __builtin_amdgcn_mfma_f32_16x16x32_bf16(bk0, aq[0][0], sacc[0][t], 0, 0, 0);
            sacc[0][t] = __builtin_amdgcn_mfma_f32_16x16x32_bf16(bk1, aq[0][1], sacc[0][t], 0, 0, 0);
            sacc[1][t] = __builtin_amdgcn_mfma_f32_16x16x32_bf16(bk0, aq[1][0], sacc[1][t], 0, 0, 0);
            sacc[1][t] = __builtin_amdgcn_mfma_f32_16x16x32_bf16(bk1, aq[1][1], sacc[1][t], 0, 0, 0);
        }

        const bool need_mask = (j0 == q0) || (q0 >= WIN && j0 == kstart);
#pragma unroll
        for (int hh = 0; hh < 2; ++hh) {
            float sv[4][4];
            if (need_mask) {
#pragma unroll
                for (int t = 0; t < 4; ++t)
#pragma unroll
                    for (int r = 0; r < 4; ++r) {
                        int j = j0 + t * 16 + quad * 4 + r;
                        bool ok = (j <= qi) && (j + WIN >= qi);
                        sv[t][r] = ok ? sacc[hh][t][r] * SL2 : -1e30f;
                    }
            } else {
#pragma unroll
                for (int t = 0; t < 4; ++t)
#pragma unroll
                    for (int r = 0; r < 4; ++r) sv[t][r] = sacc[hh][t][r] * SL2;
            }
            // online softmax (exp2 domain): in-lane reduce + 2 shuffles
            float cm = -1e30f;
#pragma unroll
            for (int t = 0; t < 4; ++t)
#pragma unroll
                for (int r = 0; r < 4; ++r) cm = fmaxf(cm, sv[t][r]);
            cm = fmaxf(cm, __shfl_xor(cm, 16));
            cm = fmaxf(cm, __shfl_xor(cm, 32));
            float mn = fmaxf(m[hh], cm);
            float alpha = exp2f(m[hh] - mn);
            m[hh] = mn;
            float sp = 0.f;
#pragma unroll
            for (int t = 0; t < 4; ++t)
#pragma unroll
                for (int r = 0; r < 4; ++r) { sv[t][r] = exp2f(sv[t][r] - mn); sp += sv[t][r]; }
            sp += __shfl_xor(sp, 16);
            sp += __shfl_xor(sp, 32);
            l[hh] = l[hh] * alpha + sp;
#pragma unroll
            for (int t = 0; t < 4; ++t)
#pragma unroll
                for (int r = 0; r < 4; ++r) acc_o[hh][t][r] *= alpha;
            // P^T -> per-head LDS slot (packed b64; wave-private, in-order)
#pragma unroll
            for (int t = 0; t < 4; ++t) {
                alignas(8) __hip_bfloat16 hp[4];
#pragma unroll
                for (int r = 0; r < 4; ++r) hp[r] = __float2bfloat16(sv[t][r]);
                *reinterpret_cast<ushort4*>(&ldsP[wave][hh][l16][t * 16 + quad * 4]) =
                    *reinterpret_cast<ushort4*>(hp);
            }
        }

        // O^T += VT @ P^T — VT fragments read once, feed both heads
#pragma unroll
        for (int ks = 0; ks < 2; ++ks) {
            short8 pf0 = *reinterpret_cast<const short8*>(
                &ldsP[wave][0][l16][ks * 32 + quad * 8]);
            short8 pf1 = *reinterpret_cast<const short8*>(
                &ldsP[wave][1][l16][ks * 32 + quad * 8]);
#pragma unroll
            for (int t = 0; t < 4; ++t) {
                const __hip_bfloat16* vrow = &ldsVT[buf][t * 16 + l16][0];
                short8 vf = *reinterpret_cast<const short8*>(
                    vrow + (((ks * 4 + quad) ^ sw) * 8));
                acc_o[0][t] = __builtin_amdgcn_mfma_f32_16x16x32_bf16(vf, pf0, acc_o[0][t], 0, 0, 0);
                acc_o[1][t] = __builtin_amdgcn_mfma_f32_16x16x32_bf16(vf, pf1, acc_o[1][t], 0, 0, 0);
            }
        }
        buf ^= 1;
    }

#pragma unroll
    for (int hh = 0; hh < 2; ++hh) {
        float inv = 1.f / l[hh];
        __hip_bfloat16* op =
            O + (size_t)(b * S_LEN + qi) * (NH * HD) + (2 * kvh + hh) * HD;
#pragma unroll
        for (int t = 0; t < 4; ++t) {
            alignas(8) __hip_bfloat16 ho[4];
#pragma unroll
            for (int r = 0; r < 4; ++r) ho[r] = __float2bfloat16(acc_o[hh][t][r] * inv);
            *reinterpret_cast<ushort4*>(op + t * 16 + quad * 4) =
                *reinterpret_cast<ushort4*>(ho);
        }
    }
}

// ---------------- launch ----------------
extern "C" void kernel_launch(void* const* d_in, const int* in_sizes, int n_in,
                              void* d_out, int out_size, void* d_ws, size_t ws_size,
                              hipStream_t stream) {
    const float* X  = (const float*)d_in[0];
    const float* Wq = (const float*)d_in[1];
    const float* Wk = (const float*)d_in[2];
    const float* Wv = (const float*)d_in[3];
    const float* Wo = (const float*)d_in[4];
    float* out = (float*)d_out;

    const int ROWS = 2 * S_LEN;               // 4096
    char* ws = (char*)d_ws;
    size_t off = 0;
    __hip_bfloat16* Xb     = (__hip_bfloat16*)(ws + off); off += (size_t)ROWS * DMODEL * 2;
    __hip_bfloat16* WqkvT  = (__hip_bfloat16*)(ws + off); off += (size_t)2048 * DMODEL * 2;
    __hip_bfloat16* WoT    = (__hip_bfloat16*)(ws + off); off += (size_t)DMODEL * DMODEL * 2;
    __hip_bfloat16* Qb     = (__hip_bfloat16*)(ws + off); off += (size_t)ROWS * (NH * HD) * 2;
    __hip_bfloat16* Kb     = (__hip_bfloat16*)(ws + off); off += (size_t)ROWS * (NKV * HD) * 2;
    __hip_bfloat16* VTg    = (__hip_bfloat16*)(ws + off); off += (size_t)ROWS * (NKV * HD) * 2;
    __hip_bfloat16* Ob     = (__hip_bfloat16*)(ws + off); off += (size_t)ROWS * (NH * HD) * 2;

    // 1. cast X; fused transpose of all weights
    cast_bf16_kernel<<<(ROWS * DMODEL) / (256 * 4), 256, 0, stream>>>(X, Xb, ROWS * DMODEL);
    transpose_cast4_kernel<<<dim3(32, 32, 4), dim3(32, 8), 0, stream>>>(
        Wq, Wk, Wv, Wo, WqkvT, WoT);

    // 2. fused QKV projection + in-register RoPE (Q,K) + V transpose (DMA dbuf)
    gemm256_kernel<0><<<dim3(2048 / 128, ROWS / 128), 256, 0, stream>>>(
        Xb, WqkvT, Qb, Kb, VTg, 2048, DMODEL);

    // 3. MFMA flash attention (GQA head-shared, DMA dbuf, swizzled)
    attn_mfma_kernel<<<dim3(S_LEN / 64, NKV, 2), 256, 0, stream>>>(Qb, Kb, VTg, Ob);

    // 4. output projection -> fp32 (DMA dbuf)
    gemm256_kernel<1><<<dim3(DMODEL / 128, ROWS / 128), 256, 0, stream>>>(
        Ob, WoT, out, nullptr, nullptr, DMODEL, DMODEL);
}

// Round 13
// 166.951 us; speedup vs baseline: 1.0474x; 1.0048x over previous
//
#include <hip/hip_runtime.h>
#include <hip/hip_bf16.h>

typedef __attribute__((ext_vector_type(8))) short short8;
typedef __attribute__((ext_vector_type(4))) float f32x4;

#define S_LEN 2048
#define NH 16
#define NKV 8
#define HD 64
#define WIN 512
#define DMODEL 1024
#define LOG2_10000 13.287712379549449f

// async 16B global -> LDS (wave-uniform LDS base + lane*16 semantics)
#define GLOAD16(g, l)                                                        \
    __builtin_amdgcn_global_load_lds(                                        \
        (const __attribute__((address_space(1))) unsigned int*)(g),          \
        (__attribute__((address_space(3))) unsigned int*)(l), 16, 0, 0)

// ---------------- cast X (fp32 -> bf16), vectorized ----------------
__global__ void cast_bf16_kernel(const float* __restrict__ X,
                                 __hip_bfloat16* __restrict__ Y, int n) {
    int i = (blockIdx.x * 256 + threadIdx.x) * 4;
    if (i + 3 < n) {
        float4 v = *reinterpret_cast<const float4*>(X + i);
        Y[i + 0] = __float2bfloat16(v.x);
        Y[i + 1] = __float2bfloat16(v.y);
        Y[i + 2] = __float2bfloat16(v.z);
        Y[i + 3] = __float2bfloat16(v.w);
    }
}

// ------- fused transpose+cast of all 4 weights (z selects matrix) -------
__global__ void transpose_cast4_kernel(const float* __restrict__ W0,
                                       const float* __restrict__ W1,
                                       const float* __restrict__ W2,
                                       const float* __restrict__ W3,
                                       __hip_bfloat16* __restrict__ WqkvT,
                                       __hip_bfloat16* __restrict__ WoT) {
    __shared__ float tile[32][33];
    const int K = DMODEL;
    const float* W;
    __hip_bfloat16* WT;
    int N;
    switch (blockIdx.z) {
        case 0: W = W0; WT = WqkvT;                          N = 1024; break;
        case 1: W = W1; WT = WqkvT + (size_t)1024 * K;       N = 512;  break;
        case 2: W = W2; WT = WqkvT + (size_t)1536 * K;       N = 512;  break;
        default: W = W3; WT = WoT;                           N = 1024; break;
    }
    if ((int)blockIdx.x * 32 >= N) return;
    int nx = blockIdx.x * 32 + threadIdx.x;
    int k0 = blockIdx.y * 32;
#pragma unroll
    for (int r = 0; r < 4; ++r) {
        int k = k0 + threadIdx.y + r * 8;
        tile[threadIdx.y + r * 8][threadIdx.x] = W[(size_t)k * N + nx];
    }
    __syncthreads();
#pragma unroll
    for (int r = 0; r < 4; ++r) {
        int nn = blockIdx.x * 32 + threadIdx.y + r * 8;
        int kk = k0 + threadIdx.x;
        WT[(size_t)nn * K + kk] = __float2bfloat16(tile[threadIdx.x][threadIdx.y + r * 8]);
    }
}

// ------------- GEMM: 128(M)x64(N) tile, 128 thr = 2 waves, DMA dbuf -----------
// ROUND 13: r12's 128x128/256-thr tile gave QKV only 512 blocks (2/CU) and
// out-proj 256 (1/CU) — grid-starved (m102: 320 TF at grid~256 vs 833 at
// ~1024). Halved tile N: wave-tile stays 64x64 (wave w = rows 64w, all 64
// cols). QKV grid 1024 (4/CU), out-proj 512 (2/CU); LDS 24 KB/block.
// MODE 0: fused QKV epilogue, in-register RoPE on Q/K (__cosf/__sinf ONLY —
//         libm calls spill the acc array). MODE 1: fp32 C.
template <int MODE>
__global__ __launch_bounds__(128) void gemm128_kernel(
    const __hip_bfloat16* __restrict__ A,
    const __hip_bfloat16* __restrict__ BT,
    void* __restrict__ o0, void* __restrict__ o1, void* __restrict__ o2,
    int N, int K) {
    __shared__ __hip_bfloat16 ldsA[2][128 * 32];   // 16 KB
    __shared__ __hip_bfloat16 ldsB[2][64 * 32];    // 8 KB
    const int tx = threadIdx.x;
    const int wave = tx >> 6;
    const int lane = tx & 63;
    const int l16 = lane & 15;
    const int quad = lane >> 4;
    const int col0 = blockIdx.x * 64;
    const int row0 = blockIdx.y * 128;
    const int wrow = wave * 64;

    f32x4 acc[4][4] = {};

    const int arow = tx >> 2;            // 0..31
    const int kc8 = (tx & 3) * 8;
    const __hip_bfloat16* gA = A + (size_t)(row0 + arow) * K + kc8;
    const __hip_bfloat16* gB = BT + (size_t)(col0 + arow) * K + kc8;

    auto stage = [&](int k0, int bf) {
        char* lA = (char*)(&ldsA[bf][0]) + tx * 16;
        char* lB = (char*)(&ldsB[bf][0]) + tx * 16;
#pragma unroll
        for (int r = 0; r < 4; ++r)
            GLOAD16(gA + (size_t)(r * 32) * K + k0, lA + r * 2048);
#pragma unroll
        for (int r = 0; r < 2; ++r)
            GLOAD16(gB + (size_t)(r * 32) * K + k0, lB + r * 2048);
    };

    stage(0, 0);
    int buf = 0;
    for (int k0 = 0; k0 < K; k0 += 32) {
        __syncthreads();                            // drains DMA into [buf]
        if (k0 + 32 < K) stage(k0 + 32, buf ^ 1);   // lands by next barrier
        short8 af[4], bf4[4];
#pragma unroll
        for (int i = 0; i < 4; ++i) {
            af[i] = *reinterpret_cast<const short8*>(
                &ldsA[buf][0] + (wrow + i * 16 + l16) * 32 + quad * 8);
            bf4[i] = *reinterpret_cast<const short8*>(
                &ldsB[buf][0] + (i * 16 + l16) * 32 + quad * 8);
        }
#pragma unroll
        for (int mi = 0; mi < 4; ++mi)
#pragma unroll
            for (int ni = 0; ni < 4; ++ni)
                acc[mi][ni] = __builtin_amdgcn_mfma_f32_16x16x32_bf16(
                    af[mi], bf4[ni], acc[mi][ni], 0, 0, 0);
        buf ^= 1;
    }

    const int rbase = row0 + wrow;
    if (MODE == 0) {
        const int cbaseg = col0;                    // 64-aligned global col
        const bool isQ = (cbaseg < DMODEL);
        const bool isK = (cbaseg >= DMODEL) && (cbaseg < DMODEL + 512);
        if (isQ || isK) {
            float invf[2];
            invf[0] = exp2f(-(float)(l16)      * (LOG2_10000 / 32.0f));
            invf[1] = exp2f(-(float)(16 + l16) * (LOG2_10000 / 32.0f));
#pragma unroll
            for (int mi = 0; mi < 4; ++mi)
#pragma unroll
                for (int r = 0; r < 4; ++r) {
                    int srow = (rbase + mi * 16 + quad * 4 + r) & (S_LEN - 1);
#pragma unroll
                    for (int ni = 0; ni < 2; ++ni) {
                        float ang = (float)srow * invf[ni];
                        float c = __cosf(ang), s = __sinf(ang);
                        float x1 = acc[mi][ni][r], x2 = acc[mi][ni + 2][r];
                        acc[mi][ni][r]     = x1 * c - x2 * s;
                        acc[mi][ni + 2][r] = x2 * c + x1 * s;
                    }
                }
            __hip_bfloat16* Co = (__hip_bfloat16*)(isQ ? o0 : o1);
            int cbase = isQ ? cbaseg : cbaseg - DMODEL;
            int rowstride = isQ ? (NH * HD) : (NKV * HD);
#pragma unroll
            for (int mi = 0; mi < 4; ++mi)
#pragma unroll
                for (int ni = 0; ni < 4; ++ni) {
                    size_t col = cbase + ni * 16 + l16;
#pragma unroll
                    for (int r = 0; r < 4; ++r)
                        Co[(size_t)(rbase + mi * 16 + quad * 4 + r) * rowstride + col] =
                            __float2bfloat16(acc[mi][ni][r]);
                }
        } else {                                   // V region -> transposed VT
            __hip_bfloat16* VTo = (__hip_bfloat16*)o2;
            int bb = row0 >> 11;
#pragma unroll
            for (int mi = 0; mi < 4; ++mi) {
                int s = ((rbase + mi * 16 + quad * 4) & (S_LEN - 1));
#pragma unroll
                for (int ni = 0; ni < 4; ++ni) {
                    int colv = cbaseg - 1536 + ni * 16 + l16;   // 0..511
                    int vh = colv >> 6, d = colv & 63;
                    alignas(8) __hip_bfloat16 hv[4];
#pragma unroll
                    for (int r = 0; r < 4; ++r) hv[r] = __float2bfloat16(acc[mi][ni][r]);
                    *reinterpret_cast<ushort4*>(
                        VTo + ((size_t)(bb * NKV + vh) * HD + d) * S_LEN + s) =
                        *reinterpret_cast<ushort4*>(hv);
                }
            }
        }
    } else {                                       // fp32 C
        float* Co = (float*)o0;
#pragma unroll
        for (int mi = 0; mi < 4; ++mi)
#pragma unroll
            for (int ni = 0; ni < 4; ++ni) {
                size_t col = col0 + ni * 16 + l16;
#pragma unroll
                for (int r = 0; r < 4; ++r)
                    Co[(size_t)(rbase + mi * 16 + quad * 4 + r) * N + col] = acc[mi][ni][r];
            }
    }
}

// ---------------- MFMA flash attention: GQA head-shared, DMA dbuf, swizzled ----
__global__ __launch_bounds__(256, 3) void attn_mfma_kernel(
    const __hip_bfloat16* __restrict__ Q,
    const __hip_bfloat16* __restrict__ K,
    const __hip_bfloat16* __restrict__ VT,
    __hip_bfloat16* __restrict__ O) {
    __shared__ __hip_bfloat16 ldsK[2][64][64];       // 16 KB
    __shared__ __hip_bfloat16 ldsVT[2][64][64];      // 16 KB
    __shared__ __hip_bfloat16 ldsP[4][2][16][80];    // 20.5 KB
    const int tx = threadIdx.x;
    const int wave = tx >> 6;
    const int lane = tx & 63;
    const int l16 = lane & 15;
    const int quad = lane >> 4;
    const int q0 = blockIdx.x * 64;
    const int kvh = blockIdx.y;
    const int b = blockIdx.z;
    const int qi = q0 + wave * 16 + l16;

    short8 aq[2][2];
#pragma unroll
    for (int hh = 0; hh < 2; ++hh) {
        const __hip_bfloat16* qp =
            Q + (size_t)(b * S_LEN + qi) * (NH * HD) + (2 * kvh + hh) * HD + quad * 8;
        aq[hh][0] = *reinterpret_cast<const short8*>(qp);
        aq[hh][1] = *reinterpret_cast<const short8*>(qp + 32);
    }
    f32x4 acc_o[2][4] = {};
    float m[2] = {-1e30f, -1e30f}, l[2] = {0.f, 0.f};
    const float SL2 = 0.125f * 1.4426950408889634f;   // scale * log2(e)

    // staging: row = tx>>3 (+32), chunk-in-row = tx&7, XOR source swizzle
    const int s_row = tx >> 3;
    const int s_c8 = (((tx & 7) ^ (s_row & 7))) * 8;
    const int sw = (l16 & 7);                          // reader swizzle key
    auto stage = [&](int j0, int bf) {
        char* lk = (char*)(&ldsK[bf][0][0]) + tx * 16;
        char* lv = (char*)(&ldsVT[bf][0][0]) + tx * 16;
#pragma unroll
        for (int r = 0; r < 2; ++r) {
            int row = s_row + r * 32;
            GLOAD16(K + (size_t)(b * S_LEN + j0 + row) * (NKV * HD) + kvh * HD + s_c8,
                    lk + r * 4096);
            GLOAD16(VT + ((size_t)(b * NKV + kvh) * HD + row) * S_LEN + j0 + s_c8,
                    lv + r * 4096);
        }
    };

    const int kstart = (q0 >= WIN) ? (q0 - WIN) : 0;
    stage(kstart, 0);
    int buf = 0;

    for (int j0 = kstart; j0 <= q0; j0 += 64) {
        __syncthreads();                              // drains DMA into [buf]
        if (j0 + 64 <= q0) stage(j0 + 64, buf ^ 1);   // async, lands by next barrier

        // S^T = K @ Q^T for BOTH heads; K fragments read once
        f32x4 sacc[2][4] = {};
#pragma unroll
        for (int t = 0; t < 4; ++t) {
            const __hip_bfloat16* krow = &ldsK[buf][t * 16 + l16][0];
            short8 bk0 = *reinterpret_cast<const short8*>(krow + ((quad ^ sw) * 8));
            short8 bk1 = *reinterpret_cast<const short8*>(krow + (((4 + quad) ^ sw) * 8));
            sacc[0][t] = __builtin_amdgcn_mfma_f32_16x16x32_bf16(bk0, aq[0][0], sacc[0][t], 0, 0, 0);
            sacc[0][t] = __builtin_amdgcn_mfma_f32_16x16x32_bf16(bk1, aq[0][1], sacc[0][t], 0, 0, 0);
            sacc[1][t] = __builtin_amdgcn_mfma_f32_16x16x32_bf16(bk0, aq[1][0], sacc[1][t], 0, 0, 0);
            sacc[1][t] = __builtin_amdgcn_mfma_f32_16x16x32_bf16(bk1, aq[1][1], sacc[1][t], 0, 0, 0);
        }

        const bool need_mask = (j0 == q0) || (q0 >= WIN && j0 == kstart);
#pragma unroll
        for (int hh = 0; hh < 2; ++hh) {
            float sv[4][4];
            if (need_mask) {
#pragma unroll
                for (int t = 0; t < 4; ++t)
#pragma unroll
                    for (int r = 0; r < 4; ++r) {
                        int j = j0 + t * 16 + quad * 4 + r;
                        bool ok = (j <= qi) && (j + WIN >= qi);
                        sv[t][r] = ok ? sacc[hh][t][r] * SL2 : -1e30f;
                    }
            } else {
#pragma unroll
                for (int t = 0; t < 4; ++t)
#pragma unroll
                    for (int r = 0; r < 4; ++r) sv[t][r] = sacc[hh][t][r] * SL2;
            }
            // online softmax (exp2 domain): in-lane reduce + 2 shuffles
            float cm = -1e30f;
#pragma unroll
            for (int t = 0; t < 4; ++t)
#pragma unroll
                for (int r = 0; r < 4; ++r) cm = fmaxf(cm, sv[t][r]);
            cm = fmaxf(cm, __shfl_xor(cm, 16));
            cm = fmaxf(cm, __shfl_xor(cm, 32));
            float mn = fmaxf(m[hh], cm);
            float alpha = exp2f(m[hh] - mn);
            m[hh] = mn;
            float sp = 0.f;
#pragma unroll
            for (int t = 0; t < 4; ++t)
#pragma unroll
                for (int r = 0; r < 4; ++r) { sv[t][r] = exp2f(sv[t][r] - mn); sp += sv[t][r]; }
            sp += __shfl_xor(sp, 16);
            sp += __shfl_xor(sp, 32);
            l[hh] = l[hh] * alpha + sp;
#pragma unroll
            for (int t = 0; t < 4; ++t)
#pragma unroll
                for (int r = 0; r < 4; ++r) acc_o[hh][t][r] *= alpha;
            // P^T -> per-head LDS slot (packed b64; wave-private, in-order)
#pragma unroll
            for (int t = 0; t < 4; ++t) {
                alignas(8) __hip_bfloat16 hp[4];
#pragma unroll
                for (int r = 0; r < 4; ++r) hp[r] = __float2bfloat16(sv[t][r]);
                *reinterpret_cast<ushort4*>(&ldsP[wave][hh][l16][t * 16 + quad * 4]) =
                    *reinterpret_cast<ushort4*>(hp);
            }
        }

        // O^T += VT @ P^T — VT fragments read once, feed both heads
#pragma unroll
        for (int ks = 0; ks < 2; ++ks) {
            short8 pf0 = *reinterpret_cast<const short8*>(
                &ldsP[wave][0][l16][ks * 32 + quad * 8]);
            short8 pf1 = *reinterpret_cast<const short8*>(
                &ldsP[wave][1][l16][ks * 32 + quad * 8]);
#pragma unroll
            for (int t = 0; t < 4; ++t) {
                const __hip_bfloat16* vrow = &ldsVT[buf][t * 16 + l16][0];
                short8 vf = *reinterpret_cast<const short8*>(
                    vrow + (((ks * 4 + quad) ^ sw) * 8));
                acc_o[0][t] = __builtin_amdgcn_mfma_f32_16x16x32_bf16(vf, pf0, acc_o[0][t], 0, 0, 0);
                acc_o[1][t] = __builtin_amdgcn_mfma_f32_16x16x32_bf16(vf, pf1, acc_o[1][t], 0, 0, 0);
            }
        }
        buf ^= 1;
    }

#pragma unroll
    for (int hh = 0; hh < 2; ++hh) {
        float inv = 1.f / l[hh];
        __hip_bfloat16* op =
            O + (size_t)(b * S_LEN + qi) * (NH * HD) + (2 * kvh + hh) * HD;
#pragma unroll
        for (int t = 0; t < 4; ++t) {
            alignas(8) __hip_bfloat16 ho[4];
#pragma unroll
            for (int r = 0; r < 4; ++r) ho[r] = __float2bfloat16(acc_o[hh][t][r] * inv);
            *reinterpret_cast<ushort4*>(op + t * 16 + quad * 4) =
                *reinterpret_cast<ushort4*>(ho);
        }
    }
}

// ---------------- launch ----------------
extern "C" void kernel_launch(void* const* d_in, const int* in_sizes, int n_in,
                              void* d_out, int out_size, void* d_ws, size_t ws_size,
                              hipStream_t stream) {
    const float* X  = (const float*)d_in[0];
    const float* Wq = (const float*)d_in[1];
    const float* Wk = (const float*)d_in[2];
    const float* Wv = (const float*)d_in[3];
    const float* Wo = (const float*)d_in[4];
    float* out = (float*)d_out;

    const int ROWS = 2 * S_LEN;               // 4096
    char* ws = (char*)d_ws;
    size_t off = 0;
    __hip_bfloat16* Xb     = (__hip_bfloat16*)(ws + off); off += (size_t)ROWS * DMODEL * 2;
    __hip_bfloat16* WqkvT  = (__hip_bfloat16*)(ws + off); off += (size_t)2048 * DMODEL * 2;
    __hip_bfloat16* WoT    = (__hip_bfloat16*)(ws + off); off += (size_t)DMODEL * DMODEL * 2;
    __hip_bfloat16* Qb     = (__hip_bfloat16*)(ws + off); off += (size_t)ROWS * (NH * HD) * 2;
    __hip_bfloat16* Kb     = (__hip_bfloat16*)(ws + off); off += (size_t)ROWS * (NKV * HD) * 2;
    __hip_bfloat16* VTg    = (__hip_bfloat16*)(ws + off); off += (size_t)ROWS * (NKV * HD) * 2;
    __hip_bfloat16* Ob     = (__hip_bfloat16*)(ws + off); off += (size_t)ROWS * (NH * HD) * 2;

    // 1. cast X; fused transpose of all weights
    cast_bf16_kernel<<<(ROWS * DMODEL) / (256 * 4), 256, 0, stream>>>(X, Xb, ROWS * DMODEL);
    transpose_cast4_kernel<<<dim3(32, 32, 4), dim3(32, 8), 0, stream>>>(
        Wq, Wk, Wv, Wo, WqkvT, WoT);

    // 2. fused QKV projection + RoPE + V transpose (1024 blocks, 4/CU)
    gemm128_kernel<0><<<dim3(2048 / 64, ROWS / 128), 128, 0, stream>>>(
        Xb, WqkvT, Qb, Kb, VTg, 2048, DMODEL);

    // 3. MFMA flash attention (GQA head-shared, DMA dbuf, swizzled)
    attn_mfma_kernel<<<dim3(S_LEN / 64, NKV, 2), 256, 0, stream>>>(Qb, Kb, VTg, Ob);

    // 4. output projection -> fp32 (512 blocks, 2/CU)
    gemm128_kernel<1><<<dim3(DMODEL / 64, ROWS / 128), 128, 0, stream>>>(
        Ob, WoT, out, nullptr, nullptr, DMODEL, DMODEL);
}